// Round 6
// baseline (47.057 us; speedup 1.0000x reference)
//
#include <hip/hip_runtime.h>

#define B_ 2048
#define F_ 4096
#define C_ 8192
#define T_ 8
#define K_ 1024
#define S_ 8

// lit = sign>0 ? x[f] : 1-x[f]
__device__ __forceinline__ float litv(const float* xs, int f, int s) {
    float v = xs[f];
    return s > 0 ? v : 1.0f - v;
}

// One block per batch row. x and out are float32.
// Phase 1: stage f32 x-row (16 KB) into LDS.
// Phase 2: 8192 conjunction products (T=8 literals each), 32 per thread, LDS gathers -> cv (32 KB).
// Phase 3: 1024 classes, 4 per thread: max over S=8 cv gathers, f32 store.
__global__ __launch_bounds__(256) void dnf_kernel(
    const float* __restrict__ x,
    const int* __restrict__ feat,
    const int* __restrict__ sign,
    const int* __restrict__ class_conj,
    float* __restrict__ out)
{
    __shared__ float xs[F_];   // 16 KB
    __shared__ float cv[C_];   // 32 KB

    const int b = blockIdx.x;
    const int tid = threadIdx.x;

    // ---- Phase 1: stage x row (f32, 16 KB) ----
    const float4* xrow = (const float4*)(x + (size_t)b * F_);
    for (int i = tid; i < F_ / 4; i += 256)
        ((float4*)xs)[i] = xrow[i];
    __syncthreads();

    // ---- Phase 2: conjunction products ----
    for (int c = tid; c < C_; c += 256) {
        const int4* fq = (const int4*)(feat + c * T_);
        const int4* sq = (const int4*)(sign + c * T_);
        int4 f0 = fq[0], f1 = fq[1];
        int4 s0 = sq[0], s1 = sq[1];
        float p0 = litv(xs, f0.x, s0.x) * litv(xs, f0.y, s0.y);
        float p1 = litv(xs, f0.z, s0.z) * litv(xs, f0.w, s0.w);
        float p2 = litv(xs, f1.x, s1.x) * litv(xs, f1.y, s1.y);
        float p3 = litv(xs, f1.z, s1.z) * litv(xs, f1.w, s1.w);
        cv[c] = (p0 * p1) * (p2 * p3);
    }
    __syncthreads();

    // ---- Phase 3: per-class max over S=8 selected conjunctions ----
    for (int k = tid; k < K_; k += 256) {
        const int4* cc = (const int4*)(class_conj + k * S_);
        int4 c0 = cc[0], c1 = cc[1];
        float m0 = fmaxf(fmaxf(cv[c0.x], cv[c0.y]), fmaxf(cv[c0.z], cv[c0.w]));
        float m1 = fmaxf(fmaxf(cv[c1.x], cv[c1.y]), fmaxf(cv[c1.z], cv[c1.w]));
        out[(size_t)b * K_ + k] = fmaxf(m0, m1);
    }
}

extern "C" void kernel_launch(void* const* d_in, const int* in_sizes, int n_in,
                              void* d_out, int out_size, void* d_ws, size_t ws_size,
                              hipStream_t stream) {
    const float* x  = (const float*)d_in[0];
    const int* feat = (const int*)d_in[1];
    const int* sign = (const int*)d_in[2];
    const int* ccj  = (const int*)d_in[3];
    float* out      = (float*)d_out;

    dnf_kernel<<<B_, 256, 0, stream>>>(x, feat, sign, ccj, out);
}

// Round 8
// 32.327 us; speedup vs baseline: 1.4556x; 1.4556x over previous
//
#include <hip/hip_runtime.h>
#include <hip/hip_fp16.h>

#define B_ 2048
#define F_ 4096
#define C_ 8192
#define T_ 8
#define K_ 1024
#define S_ 8
#define RROWS 4

// ---------------------------------------------------------------------------
// Prepass: pk[i] = (feat<<1) | (sign>0).  Byte offset into dual table = pk<<3.
// ---------------------------------------------------------------------------
__global__ void pack_kernel(const int* __restrict__ feat,
                            const int* __restrict__ sign,
                            unsigned short* __restrict__ pk) {
    int i = blockIdx.x * blockDim.x + threadIdx.x;
    if (i < C_ * T_)
        pk[i] = (unsigned short)((feat[i] << 1) | (sign[i] > 0 ? 1 : 0));
}

// packed f16 max: ROCm 7.2 lacks __hmax2; gfx950 has v_pk_max_f16
__device__ __forceinline__ __half2 h2max(__half2 a, __half2 b) {
    unsigned int ua = *(unsigned int*)&a, ub = *(unsigned int*)&b, ur;
    asm("v_pk_max_f16 %0, %1, %2" : "=v"(ur) : "v"(ua), "v"(ub));
    return *(__half2*)&ur;
}

// read 4 rows (f16) of one sign-selected literal: 8 bytes at `off`
__device__ __forceinline__ void lit4(const char* base, unsigned off,
                                     __half2& a, __half2& b) {
    uint2 g = *reinterpret_cast<const uint2*>(base + off);
    a = *reinterpret_cast<const __half2*>(&g.x);
    b = *reinterpret_cast<const __half2*>(&g.y);
}

#define LIT_MUL(OFF)                                            \
    { __half2 la, lb; lit4(base, (OFF), la, lb);                \
      p01 = __hmul2(p01, la); p23 = __hmul2(p23, lb); }

// ---------------------------------------------------------------------------
// Fused kernel: one block per 4 batch rows.
// LDS: xs[f][s][r] f16, 16 B per feature = 64 KB. xs[f][0][*]=1-x, xs[f][1][*]=x.
// Each thread: 4 classes; per class 8 conjunctions x 8 literals; each literal
// is ONE ds_read_b64 serving all 4 rows, select-free; products via v_pk_mul_f16.
// ---------------------------------------------------------------------------
template <int USE_PACKED>
__global__ __launch_bounds__(256) void dnf_kernel(
    const float* __restrict__ x,
    const unsigned short* __restrict__ pk,
    const int* __restrict__ feat,
    const int* __restrict__ sign,
    const int* __restrict__ class_conj,
    float* __restrict__ out)
{
    __shared__ __align__(16) __half xs[F_][2][RROWS];   // 64 KB

    const int b0  = blockIdx.x * RROWS;
    const int tid = threadIdx.x;

    // ---- stage 4 rows of x as dual f16 table ----
    for (int f = tid; f < F_; f += 256) {
        float v0 = x[(size_t)(b0 + 0) * F_ + f];
        float v1 = x[(size_t)(b0 + 1) * F_ + f];
        float v2 = x[(size_t)(b0 + 2) * F_ + f];
        float v3 = x[(size_t)(b0 + 3) * F_ + f];
        __half2* q = (__half2*)&xs[f][0][0];
        q[0] = __floats2half2_rn(1.0f - v0, 1.0f - v1);  // s=0 rows 0,1
        q[1] = __floats2half2_rn(1.0f - v2, 1.0f - v3);  // s=0 rows 2,3
        q[2] = __floats2half2_rn(v0, v1);                // s=1 rows 0,1
        q[3] = __floats2half2_rn(v2, v3);                // s=1 rows 2,3
    }
    __syncthreads();

    const char* base = (const char*)xs;

    for (int kk = tid; kk < K_; kk += 256) {
        const int4* cc = (const int4*)(class_conj + kk * S_);
        int4 cA = cc[0], cB = cc[1];
        int cidx[S_] = {cA.x, cA.y, cA.z, cA.w, cB.x, cB.y, cB.z, cB.w};

        __half2 m01, m23;
        #pragma unroll
        for (int s = 0; s < S_; ++s) {
            int c = cidx[s];
            __half2 p01, p23;
            if (USE_PACKED) {
                uint4 p = ((const uint4*)pk)[c];           // 8 u16 offsets
                lit4(base, (p.x & 0xFFFFu) << 3, p01, p23);
                LIT_MUL((p.x >> 16) << 3);
                LIT_MUL((p.y & 0xFFFFu) << 3);
                LIT_MUL((p.y >> 16) << 3);
                LIT_MUL((p.z & 0xFFFFu) << 3);
                LIT_MUL((p.z >> 16) << 3);
                LIT_MUL((p.w & 0xFFFFu) << 3);
                LIT_MUL((p.w >> 16) << 3);
            } else {
                const int4* fq = (const int4*)(feat + c * T_);
                const int4* sq = (const int4*)(sign + c * T_);
                int4 f0 = fq[0], f1 = fq[1];
                int4 s0 = sq[0], s1 = sq[1];
                unsigned o;
                o = ((f0.x << 1) | (s0.x > 0 ? 1 : 0)) << 3; lit4(base, o, p01, p23);
                o = ((f0.y << 1) | (s0.y > 0 ? 1 : 0)) << 3; LIT_MUL(o);
                o = ((f0.z << 1) | (s0.z > 0 ? 1 : 0)) << 3; LIT_MUL(o);
                o = ((f0.w << 1) | (s0.w > 0 ? 1 : 0)) << 3; LIT_MUL(o);
                o = ((f1.x << 1) | (s1.x > 0 ? 1 : 0)) << 3; LIT_MUL(o);
                o = ((f1.y << 1) | (s1.y > 0 ? 1 : 0)) << 3; LIT_MUL(o);
                o = ((f1.z << 1) | (s1.z > 0 ? 1 : 0)) << 3; LIT_MUL(o);
                o = ((f1.w << 1) | (s1.w > 0 ? 1 : 0)) << 3; LIT_MUL(o);
            }
            if (s == 0) { m01 = p01; m23 = p23; }
            else        { m01 = h2max(m01, p01); m23 = h2max(m23, p23); }
        }

        float2 f01 = __half22float2(m01);
        float2 f23 = __half22float2(m23);
        out[(size_t)(b0 + 0) * K_ + kk] = f01.x;
        out[(size_t)(b0 + 1) * K_ + kk] = f01.y;
        out[(size_t)(b0 + 2) * K_ + kk] = f23.x;
        out[(size_t)(b0 + 3) * K_ + kk] = f23.y;
    }
}

extern "C" void kernel_launch(void* const* d_in, const int* in_sizes, int n_in,
                              void* d_out, int out_size, void* d_ws, size_t ws_size,
                              hipStream_t stream) {
    const float* x  = (const float*)d_in[0];
    const int* feat = (const int*)d_in[1];
    const int* sign = (const int*)d_in[2];
    const int* ccj  = (const int*)d_in[3];
    float* out      = (float*)d_out;

    const size_t pk_bytes = (size_t)C_ * T_ * sizeof(unsigned short);  // 128 KB
    if (ws_size >= pk_bytes) {
        unsigned short* pk = (unsigned short*)d_ws;
        pack_kernel<<<(C_ * T_ + 255) / 256, 256, 0, stream>>>(feat, sign, pk);
        dnf_kernel<1><<<B_ / RROWS, 256, 0, stream>>>(x, pk, feat, sign, ccj, out);
    } else {
        dnf_kernel<0><<<B_ / RROWS, 256, 0, stream>>>(x, nullptr, feat, sign, ccj, out);
    }
}

// Round 9
// 30.522 us; speedup vs baseline: 1.5417x; 1.0592x over previous
//
#include <hip/hip_runtime.h>
#include <hip/hip_fp16.h>

#define B_ 2048
#define F_ 4096
#define C_ 8192
#define T_ 8
#define K_ 1024
#define S_ 8
#define RROWS 4
#define TPB 512

// ---------------------------------------------------------------------------
// Prepass: pk[i] = (feat<<1) | (sign>0).  Byte offset into dual table = pk<<3.
// ---------------------------------------------------------------------------
__global__ void pack_kernel(const int* __restrict__ feat,
                            const int* __restrict__ sign,
                            unsigned short* __restrict__ pk) {
    int i = blockIdx.x * blockDim.x + threadIdx.x;
    if (i < C_ * T_)
        pk[i] = (unsigned short)((feat[i] << 1) | (sign[i] > 0 ? 1 : 0));
}

// packed f16 max: ROCm 7.2 lacks __hmax2; gfx950 has v_pk_max_f16
__device__ __forceinline__ __half2 h2max(__half2 a, __half2 b) {
    unsigned int ua = *(unsigned int*)&a, ub = *(unsigned int*)&b, ur;
    asm("v_pk_max_f16 %0, %1, %2" : "=v"(ur) : "v"(ua), "v"(ub));
    return *(__half2*)&ur;
}

// read 4 rows (f16) of one sign-selected literal: 8 bytes at `off`
__device__ __forceinline__ void lit4(const char* base, unsigned off,
                                     __half2& a, __half2& b) {
    uint2 g = *reinterpret_cast<const uint2*>(base + off);
    a = *reinterpret_cast<const __half2*>(&g.x);
    b = *reinterpret_cast<const __half2*>(&g.y);
}

#define LIT_MUL(OFF)                                            \
    { __half2 la, lb; lit4(base, (OFF), la, lb);                \
      p01 = __hmul2(p01, la); p23 = __hmul2(p23, lb); }

// product of 8 literals of conjunction c, for 4 batch rows (f16x2 pair)
template <int USE_PACKED>
__device__ __forceinline__ void conj4(const char* base,
                                      const uint4* __restrict__ pk4,
                                      const int* __restrict__ feat,
                                      const int* __restrict__ sign,
                                      int c, __half2& p01, __half2& p23) {
    if (USE_PACKED) {
        uint4 p = pk4[c];                          // 8 u16 offsets
        lit4(base, (p.x & 0xFFFFu) << 3, p01, p23);
        LIT_MUL((p.x >> 16) << 3);
        LIT_MUL((p.y & 0xFFFFu) << 3);
        LIT_MUL((p.y >> 16) << 3);
        LIT_MUL((p.z & 0xFFFFu) << 3);
        LIT_MUL((p.z >> 16) << 3);
        LIT_MUL((p.w & 0xFFFFu) << 3);
        LIT_MUL((p.w >> 16) << 3);
    } else {
        const int4* fq = (const int4*)(feat + c * T_);
        const int4* sq = (const int4*)(sign + c * T_);
        int4 f0 = fq[0], f1 = fq[1];
        int4 s0 = sq[0], s1 = sq[1];
        unsigned o;
        o = ((f0.x << 1) | (s0.x > 0 ? 1 : 0)) << 3; lit4(base, o, p01, p23);
        o = ((f0.y << 1) | (s0.y > 0 ? 1 : 0)) << 3; LIT_MUL(o);
        o = ((f0.z << 1) | (s0.z > 0 ? 1 : 0)) << 3; LIT_MUL(o);
        o = ((f0.w << 1) | (s0.w > 0 ? 1 : 0)) << 3; LIT_MUL(o);
        o = ((f1.x << 1) | (s1.x > 0 ? 1 : 0)) << 3; LIT_MUL(o);
        o = ((f1.y << 1) | (s1.y > 0 ? 1 : 0)) << 3; LIT_MUL(o);
        o = ((f1.z << 1) | (s1.z > 0 ? 1 : 0)) << 3; LIT_MUL(o);
        o = ((f1.w << 1) | (s1.w > 0 ? 1 : 0)) << 3; LIT_MUL(o);
    }
}

// ---------------------------------------------------------------------------
// Fused kernel: one 512-thread block per 4 batch rows (16 waves/CU, 4/SIMD).
// LDS: xs[f][s][r] f16, 16 B per feature = 64 KB. xs[f][0][*]=1-x, xs[f][1][*]=x.
// Each thread: 2 classes, computed interleaved (2x MLP); per class 8 conj x 8
// literals; each literal is ONE ds_read_b64 serving all 4 rows, select-free.
// ---------------------------------------------------------------------------
template <int USE_PACKED>
__global__ __launch_bounds__(TPB, 4) void dnf_kernel(
    const float* __restrict__ x,
    const unsigned short* __restrict__ pk,
    const int* __restrict__ feat,
    const int* __restrict__ sign,
    const int* __restrict__ class_conj,
    float* __restrict__ out)
{
    __shared__ __align__(16) __half xs[F_][2][RROWS];   // 64 KB

    const int b0  = blockIdx.x * RROWS;
    const int tid = threadIdx.x;

    // ---- stage 4 rows of x as dual f16 table ----
    for (int f = tid; f < F_; f += TPB) {
        float v0 = x[(size_t)(b0 + 0) * F_ + f];
        float v1 = x[(size_t)(b0 + 1) * F_ + f];
        float v2 = x[(size_t)(b0 + 2) * F_ + f];
        float v3 = x[(size_t)(b0 + 3) * F_ + f];
        __half2* q = (__half2*)&xs[f][0][0];
        q[0] = __floats2half2_rn(1.0f - v0, 1.0f - v1);  // s=0 rows 0,1
        q[1] = __floats2half2_rn(1.0f - v2, 1.0f - v3);  // s=0 rows 2,3
        q[2] = __floats2half2_rn(v0, v1);                // s=1 rows 0,1
        q[3] = __floats2half2_rn(v2, v3);                // s=1 rows 2,3
    }
    __syncthreads();

    const char* base = (const char*)xs;
    const uint4* pk4 = (const uint4*)pk;

    const int kA = tid;          // class A: 0..511
    const int kB = tid + TPB;    // class B: 512..1023
    const int4* ccA = (const int4*)(class_conj + kA * S_);
    const int4* ccB = (const int4*)(class_conj + kB * S_);
    int4 a0 = ccA[0], a1 = ccA[1];
    int4 e0 = ccB[0], e1 = ccB[1];
    int idxA[S_] = {a0.x, a0.y, a0.z, a0.w, a1.x, a1.y, a1.z, a1.w};
    int idxB[S_] = {e0.x, e0.y, e0.z, e0.w, e1.x, e1.y, e1.z, e1.w};

    __half2 mA01, mA23, mB01, mB23;
    #pragma unroll
    for (int s = 0; s < S_; ++s) {
        __half2 pA01, pA23, pB01, pB23;
        conj4<USE_PACKED>(base, pk4, feat, sign, idxA[s], pA01, pA23);
        conj4<USE_PACKED>(base, pk4, feat, sign, idxB[s], pB01, pB23);
        if (s == 0) { mA01 = pA01; mA23 = pA23; mB01 = pB01; mB23 = pB23; }
        else {
            mA01 = h2max(mA01, pA01); mA23 = h2max(mA23, pA23);
            mB01 = h2max(mB01, pB01); mB23 = h2max(mB23, pB23);
        }
    }

    float2 fA01 = __half22float2(mA01);
    float2 fA23 = __half22float2(mA23);
    float2 fB01 = __half22float2(mB01);
    float2 fB23 = __half22float2(mB23);
    out[(size_t)(b0 + 0) * K_ + kA] = fA01.x;
    out[(size_t)(b0 + 1) * K_ + kA] = fA01.y;
    out[(size_t)(b0 + 2) * K_ + kA] = fA23.x;
    out[(size_t)(b0 + 3) * K_ + kA] = fA23.y;
    out[(size_t)(b0 + 0) * K_ + kB] = fB01.x;
    out[(size_t)(b0 + 1) * K_ + kB] = fB01.y;
    out[(size_t)(b0 + 2) * K_ + kB] = fB23.x;
    out[(size_t)(b0 + 3) * K_ + kB] = fB23.y;
}

extern "C" void kernel_launch(void* const* d_in, const int* in_sizes, int n_in,
                              void* d_out, int out_size, void* d_ws, size_t ws_size,
                              hipStream_t stream) {
    const float* x  = (const float*)d_in[0];
    const int* feat = (const int*)d_in[1];
    const int* sign = (const int*)d_in[2];
    const int* ccj  = (const int*)d_in[3];
    float* out      = (float*)d_out;

    const size_t pk_bytes = (size_t)C_ * T_ * sizeof(unsigned short);  // 128 KB
    if (ws_size >= pk_bytes) {
        unsigned short* pk = (unsigned short*)d_ws;
        pack_kernel<<<(C_ * T_ + 255) / 256, 256, 0, stream>>>(feat, sign, pk);
        dnf_kernel<1><<<B_ / RROWS, TPB, 0, stream>>>(x, pk, feat, sign, ccj, out);
    } else {
        dnf_kernel<0><<<B_ / RROWS, TPB, 0, stream>>>(x, nullptr, feat, sign, ccj, out);
    }
}

// Round 10
// 24.213 us; speedup vs baseline: 1.9435x; 1.2606x over previous
//
#include <hip/hip_runtime.h>
#include <hip/hip_fp16.h>

#define B_ 2048
#define F_ 4096
#define C_ 8192
#define T_ 8
#define K_ 1024
#define S_ 8
#define RROWS 8
#define TPB 512

// ---------------------------------------------------------------------------
// Prepass: pk[i] = (feat<<1) | (sign>0).  Byte offset into dual table = pk<<4.
// ---------------------------------------------------------------------------
__global__ void pack_kernel(const int* __restrict__ feat,
                            const int* __restrict__ sign,
                            unsigned short* __restrict__ pk) {
    int i = blockIdx.x * blockDim.x + threadIdx.x;
    if (i < C_ * T_)
        pk[i] = (unsigned short)((feat[i] << 1) | (sign[i] > 0 ? 1 : 0));
}

// packed f16 max: ROCm 7.2 lacks __hmax2; gfx950 has v_pk_max_f16
__device__ __forceinline__ __half2 h2max(__half2 a, __half2 b) {
    unsigned int ua = *(unsigned int*)&a, ub = *(unsigned int*)&b, ur;
    asm("v_pk_max_f16 %0, %1, %2" : "=v"(ur) : "v"(ua), "v"(ub));
    return *(__half2*)&ur;
}

__device__ __forceinline__ __half2 u2h2(unsigned int u) { return *(__half2*)&u; }

// one literal for 8 rows: ONE ds_read_b128 (16 B) at byte offset `off`
#define LIT_INIT(OFF)                                               \
    { uint4 g = *reinterpret_cast<const uint4*>(base + (OFF));      \
      pa = u2h2(g.x); pb = u2h2(g.y); pc = u2h2(g.z); pd = u2h2(g.w); }
#define LIT_MUL(OFF)                                                \
    { uint4 g = *reinterpret_cast<const uint4*>(base + (OFF));      \
      pa = __hmul2(pa, u2h2(g.x)); pb = __hmul2(pb, u2h2(g.y));     \
      pc = __hmul2(pc, u2h2(g.z)); pd = __hmul2(pd, u2h2(g.w)); }

// product of 8 literals of conjunction c, for 8 batch rows (4x half2)
template <int USE_PACKED>
__device__ __forceinline__ void conj8(const char* base,
                                      const uint4* __restrict__ pk4,
                                      const int* __restrict__ feat,
                                      const int* __restrict__ sign,
                                      int c, __half2& pa, __half2& pb,
                                      __half2& pc, __half2& pd) {
    if (USE_PACKED) {
        uint4 p = pk4[c];                          // 8 u16 table indices
        LIT_INIT((p.x & 0xFFFFu) << 4);
        LIT_MUL ((p.x >> 16) << 4);
        LIT_MUL ((p.y & 0xFFFFu) << 4);
        LIT_MUL ((p.y >> 16) << 4);
        LIT_MUL ((p.z & 0xFFFFu) << 4);
        LIT_MUL ((p.z >> 16) << 4);
        LIT_MUL ((p.w & 0xFFFFu) << 4);
        LIT_MUL ((p.w >> 16) << 4);
    } else {
        const int4* fq = (const int4*)(feat + c * T_);
        const int4* sq = (const int4*)(sign + c * T_);
        int4 f0 = fq[0], f1 = fq[1];
        int4 s0 = sq[0], s1 = sq[1];
        unsigned o;
        o = ((f0.x << 1) | (s0.x > 0 ? 1 : 0)) << 4; LIT_INIT(o);
        o = ((f0.y << 1) | (s0.y > 0 ? 1 : 0)) << 4; LIT_MUL(o);
        o = ((f0.z << 1) | (s0.z > 0 ? 1 : 0)) << 4; LIT_MUL(o);
        o = ((f0.w << 1) | (s0.w > 0 ? 1 : 0)) << 4; LIT_MUL(o);
        o = ((f1.x << 1) | (s1.x > 0 ? 1 : 0)) << 4; LIT_MUL(o);
        o = ((f1.y << 1) | (s1.y > 0 ? 1 : 0)) << 4; LIT_MUL(o);
        o = ((f1.z << 1) | (s1.z > 0 ? 1 : 0)) << 4; LIT_MUL(o);
        o = ((f1.w << 1) | (s1.w > 0 ? 1 : 0)) << 4; LIT_MUL(o);
    }
}

// ---------------------------------------------------------------------------
// Fused kernel: one 512-thread block per 8 batch rows; grid=256 = 1 block/CU.
// LDS: xs[f][s][8 rows] f16 = 32 B per feature = 128 KB.
// Each literal is ONE ds_read_b128 serving all 8 rows, sign folded into addr.
// Each thread: 2 classes interleaved; per class 8 conj x 8 literals.
// ---------------------------------------------------------------------------
template <int USE_PACKED>
__global__ __launch_bounds__(TPB, 2) void dnf_kernel(
    const float* __restrict__ x,
    const unsigned short* __restrict__ pk,
    const int* __restrict__ feat,
    const int* __restrict__ sign,
    const int* __restrict__ class_conj,
    float* __restrict__ out)
{
    __shared__ __align__(16) __half xs[F_][2][RROWS];   // 128 KB

    const int b0  = blockIdx.x * RROWS;
    const int tid = threadIdx.x;

    // ---- stage 8 rows of x as dual f16 table ----
    for (int f = tid; f < F_; f += TPB) {
        float v0 = x[(size_t)(b0 + 0) * F_ + f];
        float v1 = x[(size_t)(b0 + 1) * F_ + f];
        float v2 = x[(size_t)(b0 + 2) * F_ + f];
        float v3 = x[(size_t)(b0 + 3) * F_ + f];
        float v4 = x[(size_t)(b0 + 4) * F_ + f];
        float v5 = x[(size_t)(b0 + 5) * F_ + f];
        float v6 = x[(size_t)(b0 + 6) * F_ + f];
        float v7 = x[(size_t)(b0 + 7) * F_ + f];
        __half2* q = (__half2*)&xs[f][0][0];
        q[0] = __floats2half2_rn(1.0f - v0, 1.0f - v1);
        q[1] = __floats2half2_rn(1.0f - v2, 1.0f - v3);
        q[2] = __floats2half2_rn(1.0f - v4, 1.0f - v5);
        q[3] = __floats2half2_rn(1.0f - v6, 1.0f - v7);
        q[4] = __floats2half2_rn(v0, v1);
        q[5] = __floats2half2_rn(v2, v3);
        q[6] = __floats2half2_rn(v4, v5);
        q[7] = __floats2half2_rn(v6, v7);
    }
    __syncthreads();

    const char* base = (const char*)xs;
    const uint4* pk4 = (const uint4*)pk;

    const int kA = tid;          // class A: 0..511
    const int kB = tid + TPB;    // class B: 512..1023
    const int4* ccA = (const int4*)(class_conj + kA * S_);
    const int4* ccB = (const int4*)(class_conj + kB * S_);
    int4 a0 = ccA[0], a1 = ccA[1];
    int4 e0 = ccB[0], e1 = ccB[1];
    int idxA[S_] = {a0.x, a0.y, a0.z, a0.w, a1.x, a1.y, a1.z, a1.w};
    int idxB[S_] = {e0.x, e0.y, e0.z, e0.w, e1.x, e1.y, e1.z, e1.w};

    __half2 mAa, mAb, mAc, mAd, mBa, mBb, mBc, mBd;
    #pragma unroll
    for (int s = 0; s < S_; ++s) {
        __half2 pAa, pAb, pAc, pAd, pBa, pBb, pBc, pBd;
        conj8<USE_PACKED>(base, pk4, feat, sign, idxA[s], pAa, pAb, pAc, pAd);
        conj8<USE_PACKED>(base, pk4, feat, sign, idxB[s], pBa, pBb, pBc, pBd);
        if (s == 0) {
            mAa = pAa; mAb = pAb; mAc = pAc; mAd = pAd;
            mBa = pBa; mBb = pBb; mBc = pBc; mBd = pBd;
        } else {
            mAa = h2max(mAa, pAa); mAb = h2max(mAb, pAb);
            mAc = h2max(mAc, pAc); mAd = h2max(mAd, pAd);
            mBa = h2max(mBa, pBa); mBb = h2max(mBb, pBb);
            mBc = h2max(mBc, pBc); mBd = h2max(mBd, pBd);
        }
    }

    float2 f;
    f = __half22float2(mAa); out[(size_t)(b0+0)*K_+kA] = f.x; out[(size_t)(b0+1)*K_+kA] = f.y;
    f = __half22float2(mAb); out[(size_t)(b0+2)*K_+kA] = f.x; out[(size_t)(b0+3)*K_+kA] = f.y;
    f = __half22float2(mAc); out[(size_t)(b0+4)*K_+kA] = f.x; out[(size_t)(b0+5)*K_+kA] = f.y;
    f = __half22float2(mAd); out[(size_t)(b0+6)*K_+kA] = f.x; out[(size_t)(b0+7)*K_+kA] = f.y;
    f = __half22float2(mBa); out[(size_t)(b0+0)*K_+kB] = f.x; out[(size_t)(b0+1)*K_+kB] = f.y;
    f = __half22float2(mBb); out[(size_t)(b0+2)*K_+kB] = f.x; out[(size_t)(b0+3)*K_+kB] = f.y;
    f = __half22float2(mBc); out[(size_t)(b0+4)*K_+kB] = f.x; out[(size_t)(b0+5)*K_+kB] = f.y;
    f = __half22float2(mBd); out[(size_t)(b0+6)*K_+kB] = f.x; out[(size_t)(b0+7)*K_+kB] = f.y;
}

extern "C" void kernel_launch(void* const* d_in, const int* in_sizes, int n_in,
                              void* d_out, int out_size, void* d_ws, size_t ws_size,
                              hipStream_t stream) {
    const float* x  = (const float*)d_in[0];
    const int* feat = (const int*)d_in[1];
    const int* sign = (const int*)d_in[2];
    const int* ccj  = (const int*)d_in[3];
    float* out      = (float*)d_out;

    const size_t pk_bytes = (size_t)C_ * T_ * sizeof(unsigned short);  // 128 KB
    if (ws_size >= pk_bytes) {
        unsigned short* pk = (unsigned short*)d_ws;
        pack_kernel<<<(C_ * T_ + 255) / 256, 256, 0, stream>>>(feat, sign, pk);
        dnf_kernel<1><<<B_ / RROWS, TPB, 0, stream>>>(x, pk, feat, sign, ccj, out);
    } else {
        dnf_kernel<0><<<B_ / RROWS, TPB, 0, stream>>>(x, nullptr, feat, sign, ccj, out);
    }
}

// Round 11
// 23.307 us; speedup vs baseline: 2.0190x; 1.0389x over previous
//
#include <hip/hip_runtime.h>
#include <hip/hip_fp16.h>

#define B_ 2048
#define F_ 4096
#define C_ 8192
#define T_ 8
#define K_ 1024
#define S_ 8
#define RROWS 8
#define TPB 1024

// ---------------------------------------------------------------------------
// Prepass: pk[i] = (feat<<1) | (sign>0).  Byte offset into dual table = pk<<4.
// ---------------------------------------------------------------------------
__global__ void pack_kernel(const int* __restrict__ feat,
                            const int* __restrict__ sign,
                            unsigned short* __restrict__ pk) {
    int i = blockIdx.x * blockDim.x + threadIdx.x;
    if (i < C_ * T_)
        pk[i] = (unsigned short)((feat[i] << 1) | (sign[i] > 0 ? 1 : 0));
}

// packed f16 max: ROCm 7.2 lacks __hmax2; gfx950 has v_pk_max_f16
__device__ __forceinline__ __half2 h2max(__half2 a, __half2 b) {
    unsigned int ua = *(unsigned int*)&a, ub = *(unsigned int*)&b, ur;
    asm("v_pk_max_f16 %0, %1, %2" : "=v"(ur) : "v"(ua), "v"(ub));
    return *(__half2*)&ur;
}

__device__ __forceinline__ __half2 u2h2(unsigned int u) { return *(__half2*)&u; }

// one literal for 8 rows: ONE ds_read_b128 (16 B) at byte offset `off`
#define LIT_INIT(OFF)                                               \
    { uint4 g = *reinterpret_cast<const uint4*>(base + (OFF));      \
      pa = u2h2(g.x); pb = u2h2(g.y); pc = u2h2(g.z); pd = u2h2(g.w); }
#define LIT_MUL(OFF)                                                \
    { uint4 g = *reinterpret_cast<const uint4*>(base + (OFF));      \
      pa = __hmul2(pa, u2h2(g.x)); pb = __hmul2(pb, u2h2(g.y));     \
      pc = __hmul2(pc, u2h2(g.z)); pd = __hmul2(pd, u2h2(g.w)); }

// product of 8 literals of conjunction c, for 8 batch rows (4x half2)
template <int USE_PACKED>
__device__ __forceinline__ void conj8(const char* base,
                                      const uint4* __restrict__ pk4,
                                      const int* __restrict__ feat,
                                      const int* __restrict__ sign,
                                      int c, __half2& pa, __half2& pb,
                                      __half2& pc, __half2& pd) {
    if (USE_PACKED) {
        uint4 p = pk4[c];                          // 8 u16 table indices
        LIT_INIT((p.x & 0xFFFFu) << 4);
        LIT_MUL ((p.x >> 16) << 4);
        LIT_MUL ((p.y & 0xFFFFu) << 4);
        LIT_MUL ((p.y >> 16) << 4);
        LIT_MUL ((p.z & 0xFFFFu) << 4);
        LIT_MUL ((p.z >> 16) << 4);
        LIT_MUL ((p.w & 0xFFFFu) << 4);
        LIT_MUL ((p.w >> 16) << 4);
    } else {
        const int4* fq = (const int4*)(feat + c * T_);
        const int4* sq = (const int4*)(sign + c * T_);
        int4 f0 = fq[0], f1 = fq[1];
        int4 s0 = sq[0], s1 = sq[1];
        unsigned o;
        o = ((f0.x << 1) | (s0.x > 0 ? 1 : 0)) << 4; LIT_INIT(o);
        o = ((f0.y << 1) | (s0.y > 0 ? 1 : 0)) << 4; LIT_MUL(o);
        o = ((f0.z << 1) | (s0.z > 0 ? 1 : 0)) << 4; LIT_MUL(o);
        o = ((f0.w << 1) | (s0.w > 0 ? 1 : 0)) << 4; LIT_MUL(o);
        o = ((f1.x << 1) | (s1.x > 0 ? 1 : 0)) << 4; LIT_MUL(o);
        o = ((f1.y << 1) | (s1.y > 0 ? 1 : 0)) << 4; LIT_MUL(o);
        o = ((f1.z << 1) | (s1.z > 0 ? 1 : 0)) << 4; LIT_MUL(o);
        o = ((f1.w << 1) | (s1.w > 0 ? 1 : 0)) << 4; LIT_MUL(o);
    }
}

// ---------------------------------------------------------------------------
// Fused kernel: one 1024-thread block per 8 batch rows; grid=256 = 1 block/CU,
// 16 waves/CU (4/SIMD). LDS: xs[f][s][8 rows] f16 = 32 B/feature = 128 KB.
// Each literal is ONE ds_read_b128 serving all 8 rows, sign folded into addr.
// Each thread: ONE class; 8 independent conjunction chains (8-way MLP).
// ---------------------------------------------------------------------------
template <int USE_PACKED>
__global__ __launch_bounds__(TPB, 4) void dnf_kernel(
    const float* __restrict__ x,
    const unsigned short* __restrict__ pk,
    const int* __restrict__ feat,
    const int* __restrict__ sign,
    const int* __restrict__ class_conj,
    float* __restrict__ out)
{
    __shared__ __align__(16) __half xs[F_][2][RROWS];   // 128 KB

    const int b0  = blockIdx.x * RROWS;
    const int tid = threadIdx.x;

    // ---- stage 8 rows of x as dual f16 table ----
    for (int f = tid; f < F_; f += TPB) {
        float v0 = x[(size_t)(b0 + 0) * F_ + f];
        float v1 = x[(size_t)(b0 + 1) * F_ + f];
        float v2 = x[(size_t)(b0 + 2) * F_ + f];
        float v3 = x[(size_t)(b0 + 3) * F_ + f];
        float v4 = x[(size_t)(b0 + 4) * F_ + f];
        float v5 = x[(size_t)(b0 + 5) * F_ + f];
        float v6 = x[(size_t)(b0 + 6) * F_ + f];
        float v7 = x[(size_t)(b0 + 7) * F_ + f];
        __half2* q = (__half2*)&xs[f][0][0];
        q[0] = __floats2half2_rn(1.0f - v0, 1.0f - v1);
        q[1] = __floats2half2_rn(1.0f - v2, 1.0f - v3);
        q[2] = __floats2half2_rn(1.0f - v4, 1.0f - v5);
        q[3] = __floats2half2_rn(1.0f - v6, 1.0f - v7);
        q[4] = __floats2half2_rn(v0, v1);
        q[5] = __floats2half2_rn(v2, v3);
        q[6] = __floats2half2_rn(v4, v5);
        q[7] = __floats2half2_rn(v6, v7);
    }
    __syncthreads();

    const char* base = (const char*)xs;
    const uint4* pk4 = (const uint4*)pk;

    const int kk = tid;                          // one class per thread
    const int4* cc = (const int4*)(class_conj + kk * S_);
    int4 a0 = cc[0], a1 = cc[1];
    int idx[S_] = {a0.x, a0.y, a0.z, a0.w, a1.x, a1.y, a1.z, a1.w};

    __half2 ma, mb, mc, md;
    #pragma unroll
    for (int s = 0; s < S_; ++s) {
        __half2 pa, pb, pc, pd;
        conj8<USE_PACKED>(base, pk4, feat, sign, idx[s], pa, pb, pc, pd);
        if (s == 0) { ma = pa; mb = pb; mc = pc; md = pd; }
        else {
            ma = h2max(ma, pa); mb = h2max(mb, pb);
            mc = h2max(mc, pc); md = h2max(md, pd);
        }
    }

    float2 f;
    f = __half22float2(ma); out[(size_t)(b0+0)*K_+kk] = f.x; out[(size_t)(b0+1)*K_+kk] = f.y;
    f = __half22float2(mb); out[(size_t)(b0+2)*K_+kk] = f.x; out[(size_t)(b0+3)*K_+kk] = f.y;
    f = __half22float2(mc); out[(size_t)(b0+4)*K_+kk] = f.x; out[(size_t)(b0+5)*K_+kk] = f.y;
    f = __half22float2(md); out[(size_t)(b0+6)*K_+kk] = f.x; out[(size_t)(b0+7)*K_+kk] = f.y;
}

extern "C" void kernel_launch(void* const* d_in, const int* in_sizes, int n_in,
                              void* d_out, int out_size, void* d_ws, size_t ws_size,
                              hipStream_t stream) {
    const float* x  = (const float*)d_in[0];
    const int* feat = (const int*)d_in[1];
    const int* sign = (const int*)d_in[2];
    const int* ccj  = (const int*)d_in[3];
    float* out      = (float*)d_out;

    const size_t pk_bytes = (size_t)C_ * T_ * sizeof(unsigned short);  // 128 KB
    if (ws_size >= pk_bytes) {
        unsigned short* pk = (unsigned short*)d_ws;
        pack_kernel<<<(C_ * T_ + 255) / 256, 256, 0, stream>>>(feat, sign, pk);
        dnf_kernel<1><<<B_ / RROWS, TPB, 0, stream>>>(x, pk, feat, sign, ccj, out);
    } else {
        dnf_kernel<0><<<B_ / RROWS, TPB, 0, stream>>>(x, nullptr, feat, sign, ccj, out);
    }
}

// Round 12
// 21.585 us; speedup vs baseline: 2.1800x; 1.0797x over previous
//
#include <hip/hip_runtime.h>
#include <hip/hip_fp16.h>

#define B_ 2048
#define F_ 4096
#define C_ 8192
#define T_ 8
#define K_ 1024
#define S_ 8
#define RROWS 8
#define TPB 1024

// ---------------------------------------------------------------------------
// Prepass: klit[s][k] = 8 packed u16 LDS-slot indices ((f<<1)|sgn) of the
// literals of conjunction class_conj[k][s].  Transposed layout so the main
// kernel's step-s load is perfectly coalesced across lanes (16 B x lane-consecutive).
// ---------------------------------------------------------------------------
__global__ void build_klit_kernel(const int* __restrict__ feat,
                                  const int* __restrict__ sign,
                                  const int* __restrict__ class_conj,
                                  uint4* __restrict__ klit) {
    int j = blockIdx.x * blockDim.x + threadIdx.x;   // j = s*K_ + k
    if (j >= K_ * S_) return;
    int k = j & (K_ - 1);
    int s = j >> 10;                                  // K_=1024
    int c = class_conj[k * S_ + s];
    const int* fr = feat + c * T_;
    const int* sr = sign + c * T_;
    unsigned t[T_];
    #pragma unroll
    for (int i = 0; i < T_; ++i)
        t[i] = (unsigned)((fr[i] << 1) | (sr[i] > 0 ? 1 : 0)) & 0xFFFFu;
    uint4 p;
    p.x = t[0] | (t[1] << 16);
    p.y = t[2] | (t[3] << 16);
    p.z = t[4] | (t[5] << 16);
    p.w = t[6] | (t[7] << 16);
    klit[j] = p;
}

// packed f16 max: ROCm 7.2 lacks __hmax2; gfx950 has v_pk_max_f16
__device__ __forceinline__ __half2 h2max(__half2 a, __half2 b) {
    unsigned int ua = *(unsigned int*)&a, ub = *(unsigned int*)&b, ur;
    asm("v_pk_max_f16 %0, %1, %2" : "=v"(ur) : "v"(ua), "v"(ub));
    return *(__half2*)&ur;
}

__device__ __forceinline__ __half2 u2h2(unsigned int u) { return *(__half2*)&u; }

// one literal for 8 rows: ONE ds_read_b128 at slot index (direct LDS indexing)
#define LIT_INIT(SLOT)                                              \
    { uint4 g = xs4[SLOT];                                          \
      pa = u2h2(g.x); pb = u2h2(g.y); pc = u2h2(g.z); pd = u2h2(g.w); }
#define LIT_MUL(SLOT)                                               \
    { uint4 g = xs4[SLOT];                                          \
      pa = __hmul2(pa, u2h2(g.x)); pb = __hmul2(pb, u2h2(g.y));     \
      pc = __hmul2(pc, u2h2(g.z)); pd = __hmul2(pd, u2h2(g.w)); }

// ---------------------------------------------------------------------------
// Fused kernel: one 1024-thread block per 8 batch rows; grid=256 = 1 block/CU.
// LDS: xs[f][s][8 rows] f16 = 32 B/feature = 128 KB (one uint4 per (f,s)).
// Each literal is ONE ds_read_b128 serving all 8 rows, sign folded into slot.
// Index stream: klit[s][kk] — coalesced 16 B/lane, no random global gathers.
// ---------------------------------------------------------------------------
__global__ __launch_bounds__(TPB, 4) void dnf_kernel(
    const float* __restrict__ x,
    const uint4* __restrict__ klit,
    float* __restrict__ out)
{
    __shared__ __align__(16) uint4 xs4[F_ * 2];   // 128 KB: slot = (f<<1)|s

    const int b0  = blockIdx.x * RROWS;
    const int tid = threadIdx.x;

    // ---- stage 8 rows of x as dual f16 table ----
    for (int f = tid; f < F_; f += TPB) {
        float v0 = x[(size_t)(b0 + 0) * F_ + f];
        float v1 = x[(size_t)(b0 + 1) * F_ + f];
        float v2 = x[(size_t)(b0 + 2) * F_ + f];
        float v3 = x[(size_t)(b0 + 3) * F_ + f];
        float v4 = x[(size_t)(b0 + 4) * F_ + f];
        float v5 = x[(size_t)(b0 + 5) * F_ + f];
        float v6 = x[(size_t)(b0 + 6) * F_ + f];
        float v7 = x[(size_t)(b0 + 7) * F_ + f];
        __half2 n01 = __floats2half2_rn(1.0f - v0, 1.0f - v1);
        __half2 n23 = __floats2half2_rn(1.0f - v2, 1.0f - v3);
        __half2 n45 = __floats2half2_rn(1.0f - v4, 1.0f - v5);
        __half2 n67 = __floats2half2_rn(1.0f - v6, 1.0f - v7);
        __half2 p01 = __floats2half2_rn(v0, v1);
        __half2 p23 = __floats2half2_rn(v2, v3);
        __half2 p45 = __floats2half2_rn(v4, v5);
        __half2 p67 = __floats2half2_rn(v6, v7);
        uint4 neg, pos;
        neg.x = *(unsigned*)&n01; neg.y = *(unsigned*)&n23;
        neg.z = *(unsigned*)&n45; neg.w = *(unsigned*)&n67;
        pos.x = *(unsigned*)&p01; pos.y = *(unsigned*)&p23;
        pos.z = *(unsigned*)&p45; pos.w = *(unsigned*)&p67;
        xs4[(f << 1) | 0] = neg;
        xs4[(f << 1) | 1] = pos;
    }
    __syncthreads();

    const int kk = tid;                          // one class per thread

    __half2 ma, mb, mc, md;
    #pragma unroll
    for (int s = 0; s < S_; ++s) {
        uint4 p = klit[s * K_ + kk];             // coalesced index load
        __half2 pa, pb, pc, pd;
        LIT_INIT(p.x & 0xFFFFu);
        LIT_MUL (p.x >> 16);
        LIT_MUL (p.y & 0xFFFFu);
        LIT_MUL (p.y >> 16);
        LIT_MUL (p.z & 0xFFFFu);
        LIT_MUL (p.z >> 16);
        LIT_MUL (p.w & 0xFFFFu);
        LIT_MUL (p.w >> 16);
        if (s == 0) { ma = pa; mb = pb; mc = pc; md = pd; }
        else {
            ma = h2max(ma, pa); mb = h2max(mb, pb);
            mc = h2max(mc, pc); md = h2max(md, pd);
        }
    }

    float2 f;
    f = __half22float2(ma); out[(size_t)(b0+0)*K_+kk] = f.x; out[(size_t)(b0+1)*K_+kk] = f.y;
    f = __half22float2(mb); out[(size_t)(b0+2)*K_+kk] = f.x; out[(size_t)(b0+3)*K_+kk] = f.y;
    f = __half22float2(mc); out[(size_t)(b0+4)*K_+kk] = f.x; out[(size_t)(b0+5)*K_+kk] = f.y;
    f = __half22float2(md); out[(size_t)(b0+6)*K_+kk] = f.x; out[(size_t)(b0+7)*K_+kk] = f.y;
}

// ---------------------------------------------------------------------------
// Fallback (no workspace): R11 structure, reads feat/sign/class_conj directly.
// ---------------------------------------------------------------------------
__global__ __launch_bounds__(TPB, 4) void dnf_kernel_nows(
    const float* __restrict__ x,
    const int* __restrict__ feat,
    const int* __restrict__ sign,
    const int* __restrict__ class_conj,
    float* __restrict__ out)
{
    __shared__ __align__(16) uint4 xs4[F_ * 2];   // 128 KB

    const int b0  = blockIdx.x * RROWS;
    const int tid = threadIdx.x;

    for (int f = tid; f < F_; f += TPB) {
        float v0 = x[(size_t)(b0 + 0) * F_ + f];
        float v1 = x[(size_t)(b0 + 1) * F_ + f];
        float v2 = x[(size_t)(b0 + 2) * F_ + f];
        float v3 = x[(size_t)(b0 + 3) * F_ + f];
        float v4 = x[(size_t)(b0 + 4) * F_ + f];
        float v5 = x[(size_t)(b0 + 5) * F_ + f];
        float v6 = x[(size_t)(b0 + 6) * F_ + f];
        float v7 = x[(size_t)(b0 + 7) * F_ + f];
        __half2 n01 = __floats2half2_rn(1.0f - v0, 1.0f - v1);
        __half2 n23 = __floats2half2_rn(1.0f - v2, 1.0f - v3);
        __half2 n45 = __floats2half2_rn(1.0f - v4, 1.0f - v5);
        __half2 n67 = __floats2half2_rn(1.0f - v6, 1.0f - v7);
        __half2 p01 = __floats2half2_rn(v0, v1);
        __half2 p23 = __floats2half2_rn(v2, v3);
        __half2 p45 = __floats2half2_rn(v4, v5);
        __half2 p67 = __floats2half2_rn(v6, v7);
        uint4 neg, pos;
        neg.x = *(unsigned*)&n01; neg.y = *(unsigned*)&n23;
        neg.z = *(unsigned*)&n45; neg.w = *(unsigned*)&n67;
        pos.x = *(unsigned*)&p01; pos.y = *(unsigned*)&p23;
        pos.z = *(unsigned*)&p45; pos.w = *(unsigned*)&p67;
        xs4[(f << 1) | 0] = neg;
        xs4[(f << 1) | 1] = pos;
    }
    __syncthreads();

    const int kk = tid;
    const int4* cc = (const int4*)(class_conj + kk * S_);
    int4 a0 = cc[0], a1 = cc[1];
    int idx[S_] = {a0.x, a0.y, a0.z, a0.w, a1.x, a1.y, a1.z, a1.w};

    __half2 ma, mb, mc, md;
    #pragma unroll
    for (int s = 0; s < S_; ++s) {
        int c = idx[s];
        const int4* fq = (const int4*)(feat + c * T_);
        const int4* sq = (const int4*)(sign + c * T_);
        int4 f0 = fq[0], f1 = fq[1];
        int4 s0 = sq[0], s1 = sq[1];
        __half2 pa, pb, pc, pd;
        unsigned o;
        o = (f0.x << 1) | (s0.x > 0 ? 1 : 0); LIT_INIT(o);
        o = (f0.y << 1) | (s0.y > 0 ? 1 : 0); LIT_MUL(o);
        o = (f0.z << 1) | (s0.z > 0 ? 1 : 0); LIT_MUL(o);
        o = (f0.w << 1) | (s0.w > 0 ? 1 : 0); LIT_MUL(o);
        o = (f1.x << 1) | (s1.x > 0 ? 1 : 0); LIT_MUL(o);
        o = (f1.y << 1) | (s1.y > 0 ? 1 : 0); LIT_MUL(o);
        o = (f1.z << 1) | (s1.z > 0 ? 1 : 0); LIT_MUL(o);
        o = (f1.w << 1) | (s1.w > 0 ? 1 : 0); LIT_MUL(o);
        if (s == 0) { ma = pa; mb = pb; mc = pc; md = pd; }
        else {
            ma = h2max(ma, pa); mb = h2max(mb, pb);
            mc = h2max(mc, pc); md = h2max(md, pd);
        }
    }

    float2 f;
    f = __half22float2(ma); out[(size_t)(b0+0)*K_+kk] = f.x; out[(size_t)(b0+1)*K_+kk] = f.y;
    f = __half22float2(mb); out[(size_t)(b0+2)*K_+kk] = f.x; out[(size_t)(b0+3)*K_+kk] = f.y;
    f = __half22float2(mc); out[(size_t)(b0+4)*K_+kk] = f.x; out[(size_t)(b0+5)*K_+kk] = f.y;
    f = __half22float2(md); out[(size_t)(b0+6)*K_+kk] = f.x; out[(size_t)(b0+7)*K_+kk] = f.y;
}

extern "C" void kernel_launch(void* const* d_in, const int* in_sizes, int n_in,
                              void* d_out, int out_size, void* d_ws, size_t ws_size,
                              hipStream_t stream) {
    const float* x  = (const float*)d_in[0];
    const int* feat = (const int*)d_in[1];
    const int* sign = (const int*)d_in[2];
    const int* ccj  = (const int*)d_in[3];
    float* out      = (float*)d_out;

    const size_t klit_bytes = (size_t)K_ * S_ * sizeof(uint4);  // 128 KB
    if (ws_size >= klit_bytes) {
        uint4* klit = (uint4*)d_ws;
        build_klit_kernel<<<(K_ * S_ + 255) / 256, 256, 0, stream>>>(feat, sign, ccj, klit);
        dnf_kernel<<<B_ / RROWS, TPB, 0, stream>>>(x, klit, out);
    } else {
        dnf_kernel_nows<<<B_ / RROWS, TPB, 0, stream>>>(x, feat, sign, ccj, out);
    }
}